// Round 2
// baseline (2879.983 us; speedup 1.0000x reference)
//
#include <hip/hip_runtime.h>
#include <hip/hip_bf16.h>
#include <math.h>

// Problem constants (B=2, S=2048, D=2048, H=16, hd=128)
#define BB 2
#define SS 2048
#define DD 2048
#define HH 16
#define HD 128
#define MM (BB * SS)                 // 4096 rows
#define SCALE 0.08838834764831845f  // 1/sqrt(128)

typedef __attribute__((ext_vector_type(8))) __bf16 bf16x8;
typedef __attribute__((ext_vector_type(4))) float f32x4;
typedef __attribute__((ext_vector_type(8))) unsigned short ushort8v;

__device__ __forceinline__ float bf2f(unsigned short u) {
    union { unsigned int u; float f; } x;
    x.u = ((unsigned int)u) << 16;
    return x.f;
}
__device__ __forceinline__ unsigned short f2bf(float f) {
    union { float f; unsigned int u; } x;
    x.f = f;
    unsigned int r = x.u + 0x7FFFu + ((x.u >> 16) & 1u);  // RNE (finite inputs)
    return (unsigned short)(r >> 16);
}

// ---------------------------------------------------------------------------
// fp32 -> bf16 cast, float4-vectorized
// ---------------------------------------------------------------------------
__global__ __launch_bounds__(256) void cast_f32_bf16(const float* __restrict__ src,
                                                     unsigned short* __restrict__ dst,
                                                     int n4) {
    int i = blockIdx.x * 256 + threadIdx.x;
    if (i >= n4) return;
    float4 v = ((const float4*)src)[i];
    ushort4 o;
    o.x = f2bf(v.x); o.y = f2bf(v.y); o.z = f2bf(v.z); o.w = f2bf(v.w);
    ((ushort4*)dst)[i] = o;
}

// ---------------------------------------------------------------------------
// RoPE cos/sin table (fp32): table[s][i], i<64. angle = s * 10000^(-2i/128)
// NOTE: explicit cosf/sinf — round-1 bug was sincosf's (sin,cos) arg order.
// ---------------------------------------------------------------------------
__global__ __launch_bounds__(64) void rope_table_kernel(float* __restrict__ cost,
                                                        float* __restrict__ sint) {
    int s = blockIdx.x;
    int i = threadIdx.x;  // 0..63
    float inv = powf(10000.0f, -((float)(2 * i) / 128.0f));
    float ang = (float)s * inv;
    cost[s * 64 + i] = cosf(ang);
    sint[s * 64 + i] = sinf(ang);
}

// ---------------------------------------------------------------------------
// bf16 MFMA GEMM (m97 structure): C[M,N] = A[M,K] * W[N,K]^T
// 128x128 tile, BK=32, 256 threads = 4 waves (2x2), per-wave 64x64 via
// 4x4 frags of mfma_f32_16x16x32_bf16. global_load_lds width=16, linear LDS.
// ---------------------------------------------------------------------------
template <bool F32OUT>
__global__ __launch_bounds__(256) void gemm_bf16(const unsigned short* __restrict__ A,
                                                 const unsigned short* __restrict__ W,
                                                 void* __restrict__ Cv,
                                                 int M, int N, int K) {
    __shared__ unsigned short As[128 * 32];  // [row][k] linear, 8KB
    __shared__ unsigned short Bs[128 * 32];  // [n][k] linear, 8KB

    int t = threadIdx.x;
    int w = t >> 6;
    int l = t & 63;
    int n0 = blockIdx.x * 128;
    int m0 = blockIdx.y * 128;
    int wr = (w >> 1) * 64;  // wave row base
    int wc = (w & 1) * 64;   // wave col base

    f32x4 acc[4][4] = {};

    int lr = l >> 2;        // row within 16-row chunk
    int lc = (l & 3) * 8;   // k element offset within row

    for (int k0 = 0; k0 < K; k0 += 32) {
        __syncthreads();
#pragma unroll
        for (int i = 0; i < 2; ++i) {
            int c = 2 * w + i;          // chunk 0..7 (16 rows = 1KB each)
            int row = c * 16 + lr;
            const unsigned short* ga = A + (size_t)(m0 + row) * K + k0 + lc;
            __builtin_amdgcn_global_load_lds(
                (const __attribute__((address_space(1))) unsigned int*)ga,
                (__attribute__((address_space(3))) unsigned int*)(As + c * 512),
                16, 0, 0);
            const unsigned short* gb = W + (size_t)(n0 + row) * K + k0 + lc;
            __builtin_amdgcn_global_load_lds(
                (const __attribute__((address_space(1))) unsigned int*)gb,
                (__attribute__((address_space(3))) unsigned int*)(Bs + c * 512),
                16, 0, 0);
        }
        __syncthreads();

        int rlane = l & 15, g = l >> 4;
        bf16x8 af[4], bfr[4];
#pragma unroll
        for (int i = 0; i < 4; ++i) {
            af[i]  = *(const bf16x8*)&As[(wr + i * 16 + rlane) * 32 + g * 8];
            bfr[i] = *(const bf16x8*)&Bs[(wc + i * 16 + rlane) * 32 + g * 8];
        }
#pragma unroll
        for (int i = 0; i < 4; ++i)
#pragma unroll
            for (int j = 0; j < 4; ++j)
                acc[i][j] = __builtin_amdgcn_mfma_f32_16x16x32_bf16(af[i], bfr[j],
                                                                   acc[i][j], 0, 0, 0);
    }

    // epilogue: D lane map (verified m89/m91): col = lane&15, row = (lane>>4)*4 + reg
    int rlane = l & 15, g = l >> 4;
#pragma unroll
    for (int i = 0; i < 4; ++i) {
#pragma unroll
        for (int r = 0; r < 4; ++r) {
            int row = m0 + wr + i * 16 + g * 4 + r;
#pragma unroll
            for (int j = 0; j < 4; ++j) {
                int col = n0 + wc + j * 16 + rlane;
                float vv = acc[i][j][r];
                if (F32OUT)
                    ((float*)Cv)[(size_t)row * N + col] = vv;
                else
                    ((unsigned short*)Cv)[(size_t)row * N + col] = f2bf(vv);
            }
        }
    }
}

// ---------------------------------------------------------------------------
// RoPE in-place on bf16 (M, D) projection. Thread = (row, h, 4 dims).
// ---------------------------------------------------------------------------
__global__ __launch_bounds__(256) void rope_apply_kernel(unsigned short* __restrict__ arr,
                                                         const float* __restrict__ cost,
                                                         const float* __restrict__ sint) {
    int idx = blockIdx.x * 256 + threadIdx.x;  // < MM*HH*16 = 1,048,576
    int i4 = (idx & 15) * 4;
    int h = (idx >> 4) & 15;
    int row = idx >> 8;       // 0..4095
    int s = row & (SS - 1);
    float4 c  = *(const float4*)&cost[s * 64 + i4];
    float4 sn = *(const float4*)&sint[s * 64 + i4];
    size_t p0 = (size_t)row * DD + h * HD + i4;
    ushort4 lo = *(ushort4*)&arr[p0];
    ushort4 hi = *(ushort4*)&arr[p0 + 64];
    ushort4 olo, ohi;
    olo.x = f2bf(bf2f(lo.x) * c.x - bf2f(hi.x) * sn.x);
    olo.y = f2bf(bf2f(lo.y) * c.y - bf2f(hi.y) * sn.y);
    olo.z = f2bf(bf2f(lo.z) * c.z - bf2f(hi.z) * sn.z);
    olo.w = f2bf(bf2f(lo.w) * c.w - bf2f(hi.w) * sn.w);
    ohi.x = f2bf(bf2f(hi.x) * c.x + bf2f(lo.x) * sn.x);
    ohi.y = f2bf(bf2f(hi.y) * c.y + bf2f(lo.y) * sn.y);
    ohi.z = f2bf(bf2f(hi.z) * c.z + bf2f(lo.z) * sn.z);
    ohi.w = f2bf(bf2f(hi.w) * c.w + bf2f(lo.w) * sn.w);
    *(ushort4*)&arr[p0] = olo;
    *(ushort4*)&arr[p0 + 64] = ohi;
}

// ---------------------------------------------------------------------------
// Causal flash attention. bf16 in / bf16 out, fp32 compute via f32 LDS tiles.
// Grid: (S/32, H, B), 256 threads. Thread: q-row r=t>>3, 8-lane group kg=t&7.
// ---------------------------------------------------------------------------
#define BQ 32
#define BKT 32

__global__ __launch_bounds__(256) void flash_attn_kernel(const unsigned short* __restrict__ q,
                                                         const unsigned short* __restrict__ k,
                                                         const unsigned short* __restrict__ v,
                                                         unsigned short* __restrict__ o) {
    __shared__ float Qs[BQ][HD + 4];
    __shared__ float Ks[BKT][HD + 4];
    __shared__ float Vs[BKT][HD + 4];
    __shared__ float Ps[BQ][BKT + 4];

    int t = threadIdx.x;
    int qt = blockIdx.x;
    int h = blockIdx.y;
    int b = blockIdx.z;
    int q0 = qt * BQ;
    size_t base = (size_t)b * SS * DD + (size_t)h * HD;

    // Load Q tile: 32x128 bf16 = 512 ushort8, 2 per thread
#pragma unroll
    for (int i = 0; i < 2; ++i) {
        int f = t + i * 256;
        int r = f >> 4;
        int u8 = (f & 15) * 8;
        ushort8v qv = *(const ushort8v*)(q + base + (size_t)(q0 + r) * DD + u8);
#pragma unroll
        for (int j = 0; j < 8; ++j) Qs[r][u8 + j] = bf2f(qv[j]);
    }

    int r = t >> 3;   // q row in tile
    int kg = t & 7;   // lane group
    int d0 = kg * 16;

    float m = -INFINITY;
    float l = 0.0f;
    float4 acc[4] = {make_float4(0, 0, 0, 0), make_float4(0, 0, 0, 0),
                     make_float4(0, 0, 0, 0), make_float4(0, 0, 0, 0)};

    for (int kt = 0; kt <= qt; ++kt) {
        __syncthreads();  // previous iteration's LDS reads complete
#pragma unroll
        for (int i = 0; i < 2; ++i) {
            int f = t + i * 256;
            int rr = f >> 4;
            int u8 = (f & 15) * 8;
            size_t krow = base + (size_t)(kt * BKT + rr) * DD + u8;
            ushort8v kv = *(const ushort8v*)(k + krow);
            ushort8v vv = *(const ushort8v*)(v + krow);
#pragma unroll
            for (int j = 0; j < 8; ++j) {
                Ks[rr][u8 + j] = bf2f(kv[j]);
                Vs[rr][u8 + j] = bf2f(vv[j]);
            }
        }
        __syncthreads();

        // ---- scores: 4 k-rows per thread ----
        float4 sum[4];
#pragma unroll
        for (int j = 0; j < 4; ++j) sum[j] = make_float4(0, 0, 0, 0);
        for (int c4 = 0; c4 < 32; ++c4) {
            float4 qv = *(const float4*)&Qs[r][c4 * 4];
#pragma unroll
            for (int j = 0; j < 4; ++j) {
                float4 kv = *(const float4*)&Ks[kg * 4 + j][c4 * 4];
                sum[j].x = fmaf(qv.x, kv.x, sum[j].x);
                sum[j].y = fmaf(qv.y, kv.y, sum[j].y);
                sum[j].z = fmaf(qv.z, kv.z, sum[j].z);
                sum[j].w = fmaf(qv.w, kv.w, sum[j].w);
            }
        }
        float s4[4];
        int qglob = q0 + r;
#pragma unroll
        for (int j = 0; j < 4; ++j) {
            float s = ((sum[j].x + sum[j].y) + (sum[j].z + sum[j].w)) * SCALE;
            int kglob = kt * BKT + kg * 4 + j;
            s4[j] = (kglob > qglob) ? -INFINITY : s;
        }

        // ---- online softmax (8-lane groups) ----
        float mt = fmaxf(fmaxf(s4[0], s4[1]), fmaxf(s4[2], s4[3]));
#pragma unroll
        for (int off = 1; off < 8; off <<= 1) mt = fmaxf(mt, __shfl_xor(mt, off));
        float mnew = fmaxf(m, mt);
        float alpha = expf(m - mnew);
        float psum = 0.0f;
#pragma unroll
        for (int j = 0; j < 4; ++j) {
            float p = expf(s4[j] - mnew);
            Ps[r][kg * 4 + j] = p;
            psum += p;
        }
#pragma unroll
        for (int off = 1; off < 8; off <<= 1) psum += __shfl_xor(psum, off);
        l = l * alpha + psum;
        m = mnew;
#pragma unroll
        for (int j = 0; j < 4; ++j) {
            acc[j].x *= alpha; acc[j].y *= alpha; acc[j].z *= alpha; acc[j].w *= alpha;
        }
        __syncthreads();  // Ps visible

        // ---- O += P * V ----
        for (int kk = 0; kk < BKT; ++kk) {
            float p = Ps[r][kk];
#pragma unroll
            for (int j = 0; j < 4; ++j) {
                float4 vv = *(const float4*)&Vs[kk][d0 + j * 4];
                acc[j].x = fmaf(p, vv.x, acc[j].x);
                acc[j].y = fmaf(p, vv.y, acc[j].y);
                acc[j].z = fmaf(p, vv.z, acc[j].z);
                acc[j].w = fmaf(p, vv.w, acc[j].w);
            }
        }
    }

    float inv = 1.0f / l;
    unsigned short* orow = o + base + (size_t)(q0 + r) * DD + d0;
#pragma unroll
    for (int j = 0; j < 4; ++j) {
        ushort4 res;
        res.x = f2bf(acc[j].x * inv);
        res.y = f2bf(acc[j].y * inv);
        res.z = f2bf(acc[j].z * inv);
        res.w = f2bf(acc[j].w * inv);
        *(ushort4*)(orow + j * 4) = res;
    }
}

// ---------------------------------------------------------------------------
extern "C" void kernel_launch(void* const* d_in, const int* in_sizes, int n_in,
                              void* d_out, int out_size, void* d_ws, size_t ws_size,
                              hipStream_t stream) {
    const float* x  = (const float*)d_in[0];
    const float* Wq = (const float*)d_in[1];
    const float* Wk = (const float*)d_in[2];
    const float* Wv = (const float*)d_in[3];
    const float* Wo = (const float*)d_in[4];
    float* out = (float*)d_out;

    char* ws = (char*)d_ws;
    const size_t MD = (size_t)MM * DD;       // 8,388,608
    const size_t WN = (size_t)DD * DD;       // 4,194,304
    unsigned short* qb   = (unsigned short*)(ws);
    unsigned short* kb   = (unsigned short*)(ws + 2 * MD);
    unsigned short* vb   = (unsigned short*)(ws + 4 * MD);
    unsigned short* ctxb = (unsigned short*)(ws + 6 * MD);
    unsigned short* xb   = (unsigned short*)(ws + 8 * MD);
    unsigned short* wqb  = (unsigned short*)(ws + 10 * MD);
    unsigned short* wkb  = (unsigned short*)(ws + 10 * MD + 2 * WN);
    unsigned short* wvb  = (unsigned short*)(ws + 10 * MD + 4 * WN);
    unsigned short* wob  = (unsigned short*)(ws + 10 * MD + 6 * WN);
    float* cost = (float*)(ws + 10 * MD + 8 * WN);
    float* sint = cost + SS * 64;
    // total: ~118.5 MB

    cast_f32_bf16<<<(int)(MD / 4 / 256), 256, 0, stream>>>(x, xb, (int)(MD / 4));
    cast_f32_bf16<<<(int)(WN / 4 / 256), 256, 0, stream>>>(Wq, wqb, (int)(WN / 4));
    cast_f32_bf16<<<(int)(WN / 4 / 256), 256, 0, stream>>>(Wk, wkb, (int)(WN / 4));
    cast_f32_bf16<<<(int)(WN / 4 / 256), 256, 0, stream>>>(Wv, wvb, (int)(WN / 4));
    cast_f32_bf16<<<(int)(WN / 4 / 256), 256, 0, stream>>>(Wo, wob, (int)(WN / 4));

    rope_table_kernel<<<SS, 64, 0, stream>>>(cost, sint);

    dim3 gemm_grid(DD / 128, MM / 128);  // (16, 32)
    gemm_bf16<false><<<gemm_grid, 256, 0, stream>>>(xb, wqb, qb, MM, DD, DD);
    gemm_bf16<false><<<gemm_grid, 256, 0, stream>>>(xb, wkb, kb, MM, DD, DD);
    gemm_bf16<false><<<gemm_grid, 256, 0, stream>>>(xb, wvb, vb, MM, DD, DD);

    rope_apply_kernel<<<MM * HH * 16 / 256, 256, 0, stream>>>(qb, cost, sint);
    rope_apply_kernel<<<MM * HH * 16 / 256, 256, 0, stream>>>(kb, cost, sint);

    flash_attn_kernel<<<dim3(SS / BQ, HH, BB), 256, 0, stream>>>(qb, kb, vb, ctxb);

    gemm_bf16<true><<<gemm_grid, 256, 0, stream>>>(ctxb, wob, out, MM, DD, DD);
}

// Round 3
// 569.490 us; speedup vs baseline: 5.0571x; 5.0571x over previous
//
#include <hip/hip_runtime.h>
#include <hip/hip_bf16.h>
#include <math.h>

// Problem constants (B=2, S=2048, D=2048, H=16, hd=128)
#define BB 2
#define SS 2048
#define DD 2048
#define HH 16
#define HD 128
#define MM (BB * SS)                 // 4096 rows
#define SCALE 0.08838834764831845f  // 1/sqrt(128)

typedef __attribute__((ext_vector_type(8))) __bf16 bf16x8;
typedef __attribute__((ext_vector_type(4))) float f32x4;
typedef __attribute__((ext_vector_type(8))) unsigned short ushort8v;

__device__ __forceinline__ float bf2f(unsigned short u) {
    union { unsigned int u; float f; } x;
    x.u = ((unsigned int)u) << 16;
    return x.f;
}
__device__ __forceinline__ unsigned short f2bf(float f) {
    union { float f; unsigned int u; } x;
    x.f = f;
    unsigned int r = x.u + 0x7FFFu + ((x.u >> 16) & 1u);  // RNE (finite inputs)
    return (unsigned short)(r >> 16);
}

// ---------------------------------------------------------------------------
// fp32 -> bf16 cast, float4-vectorized
// ---------------------------------------------------------------------------
__global__ __launch_bounds__(256) void cast_f32_bf16(const float* __restrict__ src,
                                                     unsigned short* __restrict__ dst,
                                                     int n4) {
    int i = blockIdx.x * 256 + threadIdx.x;
    if (i >= n4) return;
    float4 v = ((const float4*)src)[i];
    ushort4 o;
    o.x = f2bf(v.x); o.y = f2bf(v.y); o.z = f2bf(v.z); o.w = f2bf(v.w);
    ((ushort4*)dst)[i] = o;
}

// ---------------------------------------------------------------------------
// RoPE cos/sin table (fp32): table[s][i], i<64. angle = s * 10000^(-2i/128)
// ---------------------------------------------------------------------------
__global__ __launch_bounds__(64) void rope_table_kernel(float* __restrict__ cost,
                                                        float* __restrict__ sint) {
    int s = blockIdx.x;
    int i = threadIdx.x;  // 0..63
    float inv = powf(10000.0f, -((float)(2 * i) / 128.0f));
    float ang = (float)s * inv;
    cost[s * 64 + i] = cosf(ang);
    sint[s * 64 + i] = sinf(ang);
}

// ---------------------------------------------------------------------------
// bf16 MFMA GEMM (m97 structure): C[M,N] = A[M,K] * W[N,K]^T   (unchanged)
// ---------------------------------------------------------------------------
template <bool F32OUT>
__global__ __launch_bounds__(256) void gemm_bf16(const unsigned short* __restrict__ A,
                                                 const unsigned short* __restrict__ W,
                                                 void* __restrict__ Cv,
                                                 int M, int N, int K) {
    __shared__ unsigned short As[128 * 32];
    __shared__ unsigned short Bs[128 * 32];

    int t = threadIdx.x;
    int w = t >> 6;
    int l = t & 63;
    int n0 = blockIdx.x * 128;
    int m0 = blockIdx.y * 128;
    int wr = (w >> 1) * 64;
    int wc = (w & 1) * 64;

    f32x4 acc[4][4] = {};

    int lr = l >> 2;
    int lc = (l & 3) * 8;

    for (int k0 = 0; k0 < K; k0 += 32) {
        __syncthreads();
#pragma unroll
        for (int i = 0; i < 2; ++i) {
            int c = 2 * w + i;
            int row = c * 16 + lr;
            const unsigned short* ga = A + (size_t)(m0 + row) * K + k0 + lc;
            __builtin_amdgcn_global_load_lds(
                (const __attribute__((address_space(1))) unsigned int*)ga,
                (__attribute__((address_space(3))) unsigned int*)(As + c * 512),
                16, 0, 0);
            const unsigned short* gb = W + (size_t)(n0 + row) * K + k0 + lc;
            __builtin_amdgcn_global_load_lds(
                (const __attribute__((address_space(1))) unsigned int*)gb,
                (__attribute__((address_space(3))) unsigned int*)(Bs + c * 512),
                16, 0, 0);
        }
        __syncthreads();

        int rlane = l & 15, g = l >> 4;
        bf16x8 af[4], bfr[4];
#pragma unroll
        for (int i = 0; i < 4; ++i) {
            af[i]  = *(const bf16x8*)&As[(wr + i * 16 + rlane) * 32 + g * 8];
            bfr[i] = *(const bf16x8*)&Bs[(wc + i * 16 + rlane) * 32 + g * 8];
        }
#pragma unroll
        for (int i = 0; i < 4; ++i)
#pragma unroll
            for (int j = 0; j < 4; ++j)
                acc[i][j] = __builtin_amdgcn_mfma_f32_16x16x32_bf16(af[i], bfr[j],
                                                                   acc[i][j], 0, 0, 0);
    }

    int rlane = l & 15, g = l >> 4;
#pragma unroll
    for (int i = 0; i < 4; ++i) {
#pragma unroll
        for (int r = 0; r < 4; ++r) {
            int row = m0 + wr + i * 16 + g * 4 + r;
#pragma unroll
            for (int j = 0; j < 4; ++j) {
                int col = n0 + wc + j * 16 + rlane;
                float vv = acc[i][j][r];
                if (F32OUT)
                    ((float*)Cv)[(size_t)row * N + col] = vv;
                else
                    ((unsigned short*)Cv)[(size_t)row * N + col] = f2bf(vv);
            }
        }
    }
}

// ---------------------------------------------------------------------------
// RoPE in-place on bf16 (M, D) projection.
// ---------------------------------------------------------------------------
__global__ __launch_bounds__(256) void rope_apply_kernel(unsigned short* __restrict__ arr,
                                                         const float* __restrict__ cost,
                                                         const float* __restrict__ sint) {
    int idx = blockIdx.x * 256 + threadIdx.x;
    int i4 = (idx & 15) * 4;
    int h = (idx >> 4) & 15;
    int row = idx >> 8;
    int s = row & (SS - 1);
    float4 c  = *(const float4*)&cost[s * 64 + i4];
    float4 sn = *(const float4*)&sint[s * 64 + i4];
    size_t p0 = (size_t)row * DD + h * HD + i4;
    ushort4 lo = *(ushort4*)&arr[p0];
    ushort4 hi = *(ushort4*)&arr[p0 + 64];
    ushort4 olo, ohi;
    olo.x = f2bf(bf2f(lo.x) * c.x - bf2f(hi.x) * sn.x);
    olo.y = f2bf(bf2f(lo.y) * c.y - bf2f(hi.y) * sn.y);
    olo.z = f2bf(bf2f(lo.z) * c.z - bf2f(hi.z) * sn.z);
    olo.w = f2bf(bf2f(lo.w) * c.w - bf2f(hi.w) * sn.w);
    ohi.x = f2bf(bf2f(hi.x) * c.x + bf2f(lo.x) * sn.x);
    ohi.y = f2bf(bf2f(hi.y) * c.y + bf2f(lo.y) * sn.y);
    ohi.z = f2bf(bf2f(hi.z) * c.z + bf2f(lo.z) * sn.z);
    ohi.w = f2bf(bf2f(hi.w) * c.w + bf2f(lo.w) * sn.w);
    *(ushort4*)&arr[p0] = olo;
    *(ushort4*)&arr[p0 + 64] = ohi;
}

// ---------------------------------------------------------------------------
// MFMA causal flash attention.
// Grid (16, H, B), 256 threads = 4 waves. Block q-tile = 128 (wave = 32 q).
// KV tile = 64. Swapped QK^T (mfma(K,Q) -> S^T) so P is lane-k-contiguous.
// Ks: [c][64][32] linear (global_load_lds).  Vt: [d][k] XOR-swizzled.
// Ps: per-wave [32][72] bf16.
// ---------------------------------------------------------------------------
__global__ __launch_bounds__(256) void mfma_attn(const unsigned short* __restrict__ qm,
                                                 const unsigned short* __restrict__ km,
                                                 const unsigned short* __restrict__ vm,
                                                 unsigned short* __restrict__ om) {
    __shared__ unsigned short Ks[4 * 64 * 32];   // 16 KB
    __shared__ unsigned short Vt[128 * 64];      // 16 KB, slot-swizzled
    __shared__ unsigned short Ps[4][32 * 72];    // 18 KB

    int t = threadIdx.x;
    int w = t >> 6;
    int l = t & 63;
    int l15 = l & 15;
    int g = l >> 4;

    int qt = (int)gridDim.x - 1 - (int)blockIdx.x;  // longest blocks first
    int h = blockIdx.y;
    int b = blockIdx.z;
    int q0 = qt * 128;
    size_t bbase = (size_t)b * SS * DD + (size_t)h * HD;

    // Q fragments (B-operand): row = l15, hd-chunk = c*32 + g*8. Direct global.
    bf16x8 qf[2][4];
#pragma unroll
    for (int qg = 0; qg < 2; ++qg) {
        int qrow = q0 + w * 32 + qg * 16 + l15;
#pragma unroll
        for (int c = 0; c < 4; ++c)
            qf[qg][c] = *(const bf16x8*)(qm + bbase + (size_t)qrow * DD + c * 32 + g * 8);
    }

    f32x4 acc_o[2][8] = {};
    float m_[2] = {-INFINITY, -INFINITY};
    float l_[2] = {0.0f, 0.0f};

    int ntiles = q0 / 64 + 2;
    for (int kt = 0; kt < ntiles; ++kt) {
        __syncthreads();  // previous tile's LDS reads complete

        // ---- stage K tile: wave w stages rows w*16..w*16+15 for 4 hd-chunks ----
#pragma unroll
        for (int c = 0; c < 4; ++c) {
            const unsigned short* ga = km + bbase +
                (size_t)(kt * 64 + w * 16 + (l >> 2)) * DD + c * 32 + (l & 3) * 8;
            __builtin_amdgcn_global_load_lds(
                (const __attribute__((address_space(1))) unsigned int*)ga,
                (__attribute__((address_space(3))) unsigned int*)(Ks + c * 2048 + w * 512),
                16, 0, 0);
        }

        // ---- stage V transposed: Vt[d][k], slot-swizzle (k>>3)^((d>>3)&7) ----
        {
            int k0 = 2 * (t >> 3);   // 0..62 even
            int d8 = t & 7;
#pragma unroll
            for (int i = 0; i < 2; ++i) {
                const unsigned short* s0 = vm + bbase +
                    (size_t)(kt * 64 + k0) * DD + (d8 + 8 * i) * 8;
                ushort8v a = *(const ushort8v*)s0;
                ushort8v bb = *(const ushort8v*)(s0 + DD);
#pragma unroll
                for (int j = 0; j < 8; ++j) {
                    int d = (d8 + 8 * i) * 8 + j;
                    int swz = (k0 >> 3) ^ ((d >> 3) & 7);
                    unsigned int pack = (unsigned int)a[j] | ((unsigned int)bb[j] << 16);
                    *(unsigned int*)&Vt[d * 64 + swz * 8 + (k0 & 7)] = pack;
                }
            }
        }
        __syncthreads();  // staging visible

        bool active = (kt * 64 <= q0 + w * 32 + 31);
        if (active) {
            // ---- S^T = K * Q^T : C row = k, col = q ----
            f32x4 s_[2][4] = {};
#pragma unroll
            for (int c = 0; c < 4; ++c) {
                bf16x8 kf[4];
#pragma unroll
                for (int kg = 0; kg < 4; ++kg)
                    kf[kg] = *(const bf16x8*)&Ks[c * 2048 + (kg * 16 + l15) * 32 + g * 8];
#pragma unroll
                for (int kg = 0; kg < 4; ++kg)
#pragma unroll
                    for (int qg = 0; qg < 2; ++qg)
                        s_[qg][kg] = __builtin_amdgcn_mfma_f32_16x16x32_bf16(
                            kf[kg], qf[qg][c], s_[qg][kg], 0, 0, 0);
            }

            bool maskt = (kt * 64 + 63 > q0 + w * 32);
#pragma unroll
            for (int qg = 0; qg < 2; ++qg) {
                int qglob = q0 + w * 32 + qg * 16 + l15;
                float p[16];
                float mt = -INFINITY;
#pragma unroll
                for (int kg = 0; kg < 4; ++kg)
#pragma unroll
                    for (int r = 0; r < 4; ++r) {
                        float sv = s_[qg][kg][r] * SCALE;
                        if (maskt && (kt * 64 + kg * 16 + g * 4 + r > qglob))
                            sv = -INFINITY;
                        p[kg * 4 + r] = sv;
                        mt = fmaxf(mt, sv);
                    }
                mt = fmaxf(mt, __shfl_xor(mt, 16));
                mt = fmaxf(mt, __shfl_xor(mt, 32));
                float mnew = fmaxf(m_[qg], mt);
                float alpha = __expf(m_[qg] - mnew);
                float ps = 0.0f;
#pragma unroll
                for (int n = 0; n < 16; ++n) {
                    p[n] = __expf(p[n] - mnew);
                    ps += p[n];
                }
                ps += __shfl_xor(ps, 16);
                ps += __shfl_xor(ps, 32);
                l_[qg] = l_[qg] * alpha + ps;
                m_[qg] = mnew;

                // P -> bf16 -> LDS (b64 per kg: k = kg*16 + g*4 + 0..3, row = q)
#pragma unroll
                for (int kg = 0; kg < 4; ++kg) {
                    union { __bf16 hv[4]; uint2 u2; } pk;
#pragma unroll
                    for (int r = 0; r < 4; ++r) pk.hv[r] = (__bf16)p[kg * 4 + r];
                    *(uint2*)&Ps[w][(qg * 16 + l15) * 72 + kg * 16 + g * 4] = pk.u2;
                }

                // rescale O accumulators: O-frag row q' = 4*g + r
                float ar[4];
#pragma unroll
                for (int r = 0; r < 4; ++r) ar[r] = __shfl(alpha, 4 * g + r);
#pragma unroll
                for (int dg = 0; dg < 8; ++dg)
#pragma unroll
                    for (int r = 0; r < 4; ++r) acc_o[qg][dg][r] *= ar[r];
            }

            // ---- PV: O += P * V ----
            bf16x8 pf[2][2];
#pragma unroll
            for (int qg = 0; qg < 2; ++qg)
#pragma unroll
                for (int ks = 0; ks < 2; ++ks)
                    pf[qg][ks] = *(const bf16x8*)&Ps[w][(qg * 16 + l15) * 72 + ks * 32 + g * 8];
#pragma unroll
            for (int ks = 0; ks < 2; ++ks)
#pragma unroll
                for (int dg = 0; dg < 8; ++dg) {
                    int d = dg * 16 + l15;
                    int swz = (ks * 4 + g) ^ ((d >> 3) & 7);
                    bf16x8 vf = *(const bf16x8*)&Vt[d * 64 + swz * 8];
#pragma unroll
                    for (int qg = 0; qg < 2; ++qg)
                        acc_o[qg][dg] = __builtin_amdgcn_mfma_f32_16x16x32_bf16(
                            pf[qg][ks], vf, acc_o[qg][dg], 0, 0, 0);
                }
        }
    }

    // ---- epilogue: O / lsum -> bf16 ----
#pragma unroll
    for (int qg = 0; qg < 2; ++qg) {
        float lr[4];
#pragma unroll
        for (int r = 0; r < 4; ++r) lr[r] = 1.0f / __shfl(l_[qg], 4 * g + r);
#pragma unroll
        for (int dg = 0; dg < 8; ++dg)
#pragma unroll
            for (int r = 0; r < 4; ++r) {
                int qrow = q0 + w * 32 + qg * 16 + 4 * g + r;
                om[bbase + (size_t)qrow * DD + dg * 16 + l15] =
                    f2bf(acc_o[qg][dg][r] * lr[r]);
            }
    }
}

// ---------------------------------------------------------------------------
extern "C" void kernel_launch(void* const* d_in, const int* in_sizes, int n_in,
                              void* d_out, int out_size, void* d_ws, size_t ws_size,
                              hipStream_t stream) {
    const float* x  = (const float*)d_in[0];
    const float* Wq = (const float*)d_in[1];
    const float* Wk = (const float*)d_in[2];
    const float* Wv = (const float*)d_in[3];
    const float* Wo = (const float*)d_in[4];
    float* out = (float*)d_out;

    char* ws = (char*)d_ws;
    const size_t MD = (size_t)MM * DD;
    const size_t WN = (size_t)DD * DD;
    unsigned short* qb   = (unsigned short*)(ws);
    unsigned short* kb   = (unsigned short*)(ws + 2 * MD);
    unsigned short* vb   = (unsigned short*)(ws + 4 * MD);
    unsigned short* ctxb = (unsigned short*)(ws + 6 * MD);
    unsigned short* xb   = (unsigned short*)(ws + 8 * MD);
    unsigned short* wqb  = (unsigned short*)(ws + 10 * MD);
    unsigned short* wkb  = (unsigned short*)(ws + 10 * MD + 2 * WN);
    unsigned short* wvb  = (unsigned short*)(ws + 10 * MD + 4 * WN);
    unsigned short* wob  = (unsigned short*)(ws + 10 * MD + 6 * WN);
    float* cost = (float*)(ws + 10 * MD + 8 * WN);
    float* sint = cost + SS * 64;

    cast_f32_bf16<<<(int)(MD / 4 / 256), 256, 0, stream>>>(x, xb, (int)(MD / 4));
    cast_f32_bf16<<<(int)(WN / 4 / 256), 256, 0, stream>>>(Wq, wqb, (int)(WN / 4));
    cast_f32_bf16<<<(int)(WN / 4 / 256), 256, 0, stream>>>(Wk, wkb, (int)(WN / 4));
    cast_f32_bf16<<<(int)(WN / 4 / 256), 256, 0, stream>>>(Wv, wvb, (int)(WN / 4));
    cast_f32_bf16<<<(int)(WN / 4 / 256), 256, 0, stream>>>(Wo, wob, (int)(WN / 4));

    rope_table_kernel<<<SS, 64, 0, stream>>>(cost, sint);

    dim3 gemm_grid(DD / 128, MM / 128);
    gemm_bf16<false><<<gemm_grid, 256, 0, stream>>>(xb, wqb, qb, MM, DD, DD);
    gemm_bf16<false><<<gemm_grid, 256, 0, stream>>>(xb, wkb, kb, MM, DD, DD);
    gemm_bf16<false><<<gemm_grid, 256, 0, stream>>>(xb, wvb, vb, MM, DD, DD);

    rope_apply_kernel<<<MM * HH * 16 / 256, 256, 0, stream>>>(qb, cost, sint);
    rope_apply_kernel<<<MM * HH * 16 / 256, 256, 0, stream>>>(kb, cost, sint);

    mfma_attn<<<dim3(SS / 128, HH, BB), 256, 0, stream>>>(qb, kb, vb, ctxb);

    gemm_bf16<true><<<gemm_grid, 256, 0, stream>>>(ctxb, wob, out, MM, DD, DD);
}

// Round 4
// 516.985 us; speedup vs baseline: 5.5707x; 1.1016x over previous
//
#include <hip/hip_runtime.h>
#include <hip/hip_bf16.h>
#include <math.h>

// Problem constants (B=2, S=2048, D=2048, H=16, hd=128)
#define BB 2
#define SS 2048
#define DD 2048
#define HH 16
#define HD 128
#define MM (BB * SS)                 // 4096 rows
#define SCALE 0.08838834764831845f  // 1/sqrt(128)

typedef __attribute__((ext_vector_type(8))) __bf16 bf16x8;
typedef __attribute__((ext_vector_type(4))) float f32x4;
typedef __attribute__((ext_vector_type(8))) unsigned short ushort8v;

__device__ __forceinline__ float bf2f(unsigned short u) {
    union { unsigned int u; float f; } x;
    x.u = ((unsigned int)u) << 16;
    return x.f;
}
__device__ __forceinline__ unsigned short f2bf(float f) {
    union { float f; unsigned int u; } x;
    x.f = f;
    unsigned int r = x.u + 0x7FFFu + ((x.u >> 16) & 1u);  // RNE (finite inputs)
    return (unsigned short)(r >> 16);
}

// ---------------------------------------------------------------------------
// fp32 -> bf16 cast, float4-vectorized
// ---------------------------------------------------------------------------
__global__ __launch_bounds__(256) void cast_f32_bf16(const float* __restrict__ src,
                                                     unsigned short* __restrict__ dst,
                                                     int n4) {
    int i = blockIdx.x * 256 + threadIdx.x;
    if (i >= n4) return;
    float4 v = ((const float4*)src)[i];
    ushort4 o;
    o.x = f2bf(v.x); o.y = f2bf(v.y); o.z = f2bf(v.z); o.w = f2bf(v.w);
    ((ushort4*)dst)[i] = o;
}

// ---------------------------------------------------------------------------
// RoPE cos/sin table (fp32): table[s][i], i<64. angle = s * 10000^(-2i/128)
// ---------------------------------------------------------------------------
__global__ __launch_bounds__(64) void rope_table_kernel(float* __restrict__ cost,
                                                        float* __restrict__ sint) {
    int s = blockIdx.x;
    int i = threadIdx.x;  // 0..63
    float inv = powf(10000.0f, -((float)(2 * i) / 128.0f));
    float ang = (float)s * inv;
    cost[s * 64 + i] = cosf(ang);
    sint[s * 64 + i] = sinf(ang);
}

// ---------------------------------------------------------------------------
// bf16 MFMA GEMM (m97 structure): C[M,N] = A[M,K] * W[N,K]^T   (unchanged)
// ---------------------------------------------------------------------------
template <bool F32OUT>
__global__ __launch_bounds__(256) void gemm_bf16(const unsigned short* __restrict__ A,
                                                 const unsigned short* __restrict__ W,
                                                 void* __restrict__ Cv,
                                                 int M, int N, int K) {
    __shared__ unsigned short As[128 * 32];
    __shared__ unsigned short Bs[128 * 32];

    int t = threadIdx.x;
    int w = t >> 6;
    int l = t & 63;
    int n0 = blockIdx.x * 128;
    int m0 = blockIdx.y * 128;
    int wr = (w >> 1) * 64;
    int wc = (w & 1) * 64;

    f32x4 acc[4][4] = {};

    int lr = l >> 2;
    int lc = (l & 3) * 8;

    for (int k0 = 0; k0 < K; k0 += 32) {
        __syncthreads();
#pragma unroll
        for (int i = 0; i < 2; ++i) {
            int c = 2 * w + i;
            int row = c * 16 + lr;
            const unsigned short* ga = A + (size_t)(m0 + row) * K + k0 + lc;
            __builtin_amdgcn_global_load_lds(
                (const __attribute__((address_space(1))) unsigned int*)ga,
                (__attribute__((address_space(3))) unsigned int*)(As + c * 512),
                16, 0, 0);
            const unsigned short* gb = W + (size_t)(n0 + row) * K + k0 + lc;
            __builtin_amdgcn_global_load_lds(
                (const __attribute__((address_space(1))) unsigned int*)gb,
                (__attribute__((address_space(3))) unsigned int*)(Bs + c * 512),
                16, 0, 0);
        }
        __syncthreads();

        int rlane = l & 15, g = l >> 4;
        bf16x8 af[4], bfr[4];
#pragma unroll
        for (int i = 0; i < 4; ++i) {
            af[i]  = *(const bf16x8*)&As[(wr + i * 16 + rlane) * 32 + g * 8];
            bfr[i] = *(const bf16x8*)&Bs[(wc + i * 16 + rlane) * 32 + g * 8];
        }
#pragma unroll
        for (int i = 0; i < 4; ++i)
#pragma unroll
            for (int j = 0; j < 4; ++j)
                acc[i][j] = __builtin_amdgcn_mfma_f32_16x16x32_bf16(af[i], bfr[j],
                                                                   acc[i][j], 0, 0, 0);
    }

    int rlane = l & 15, g = l >> 4;
#pragma unroll
    for (int i = 0; i < 4; ++i) {
#pragma unroll
        for (int r = 0; r < 4; ++r) {
            int row = m0 + wr + i * 16 + g * 4 + r;
#pragma unroll
            for (int j = 0; j < 4; ++j) {
                int col = n0 + wc + j * 16 + rlane;
                float vv = acc[i][j][r];
                if (F32OUT)
                    ((float*)Cv)[(size_t)row * N + col] = vv;
                else
                    ((unsigned short*)Cv)[(size_t)row * N + col] = f2bf(vv);
            }
        }
    }
}

// ---------------------------------------------------------------------------
// RoPE in-place on bf16 (M, D) projection.
// ---------------------------------------------------------------------------
__global__ __launch_bounds__(256) void rope_apply_kernel(unsigned short* __restrict__ arr,
                                                         const float* __restrict__ cost,
                                                         const float* __restrict__ sint) {
    int idx = blockIdx.x * 256 + threadIdx.x;
    int i4 = (idx & 15) * 4;
    int h = (idx >> 4) & 15;
    int row = idx >> 8;
    int s = row & (SS - 1);
    float4 c  = *(const float4*)&cost[s * 64 + i4];
    float4 sn = *(const float4*)&sint[s * 64 + i4];
    size_t p0 = (size_t)row * DD + h * HD + i4;
    ushort4 lo = *(ushort4*)&arr[p0];
    ushort4 hi = *(ushort4*)&arr[p0 + 64];
    ushort4 olo, ohi;
    olo.x = f2bf(bf2f(lo.x) * c.x - bf2f(hi.x) * sn.x);
    olo.y = f2bf(bf2f(lo.y) * c.y - bf2f(hi.y) * sn.y);
    olo.z = f2bf(bf2f(lo.z) * c.z - bf2f(hi.z) * sn.z);
    olo.w = f2bf(bf2f(lo.w) * c.w - bf2f(hi.w) * sn.w);
    ohi.x = f2bf(bf2f(hi.x) * c.x + bf2f(lo.x) * sn.x);
    ohi.y = f2bf(bf2f(hi.y) * c.y + bf2f(lo.y) * sn.y);
    ohi.z = f2bf(bf2f(hi.z) * c.z + bf2f(lo.z) * sn.z);
    ohi.w = f2bf(bf2f(hi.w) * c.w + bf2f(lo.w) * sn.w);
    *(ushort4*)&arr[p0] = olo;
    *(ushort4*)&arr[p0 + 64] = ohi;
}

// ---------------------------------------------------------------------------
// MFMA causal flash attention v2.
// Grid (32, H, B) = 1024 blocks, 256 threads = 4 waves. Block q-tile = 64,
// wave = 16 q rows. KV tile = 64, nt = qt+1 (all waves active every iter).
// K: double-buffered LDS via global_load_lds with both-sides swizzle
//    (layout byte = row*256 + (c^((row>>2)&3))*64 + (g^(row&3))*16 -> 2-way).
// V: T14 split - global->regs at iter top, regs->Vt (transposed, slot-swizzled)
//    between the two barriers. Ps: per-wave [16][40], reused per ks-half.
// Online softmax with T13 defer-max (THR=8).
// ---------------------------------------------------------------------------
__global__ __launch_bounds__(256, 3) void mfma_attn(const unsigned short* __restrict__ qm,
                                                    const unsigned short* __restrict__ km,
                                                    const unsigned short* __restrict__ vm,
                                                    unsigned short* __restrict__ om) {
    __shared__ unsigned short Ks[2][64 * 128];   // 2 x 16 KB, swizzled layout
    __shared__ unsigned short Vt[128 * 64];      // 16 KB, slot-swizzled [d][k]
    __shared__ unsigned short Ps[4][16 * 40];    // 5 KB

    int t = threadIdx.x;
    int w = t >> 6;
    int l = t & 63;
    int l15 = l & 15;
    int g = l >> 4;

    int qt = 31 - (int)blockIdx.x;   // longest blocks first
    int h = blockIdx.y;
    int b = blockIdx.z;
    int q0 = qt * 64;
    size_t bbase = (size_t)b * SS * DD + (size_t)h * HD;

    // Q fragments (B-operand): wave w rows q0+w*16+l15, chunk c*32 + g*8
    bf16x8 qf[4];
    {
        int qrow = q0 + w * 16 + l15;
#pragma unroll
        for (int c = 0; c < 4; ++c)
            qf[c] = *(const bf16x8*)(qm + bbase + (size_t)qrow * DD + c * 32 + g * 8);
    }

    f32x4 acc_o[8] = {};
    float m_ = -INFINITY;
    float l_ = 0.0f;

    int nt = qt + 1;
    int vk0 = 2 * (t >> 3);   // 0..62 even
    int vd8 = t & 7;

    // --- staging helpers ---
    auto stage_k = [&](int kt2, int buf) {
#pragma unroll
        for (int s = 0; s < 4; ++s) {
            int row = w * 16 + s * 4 + (l >> 4);
            int c = ((l >> 2) & 3) ^ s;          // inverse swizzle on global src
            int gg = (l & 3) ^ (l >> 4);
            const unsigned short* ga = km + bbase +
                (size_t)(kt2 * 64 + row) * DD + c * 32 + gg * 8;
            __builtin_amdgcn_global_load_lds(
                (const __attribute__((address_space(1))) unsigned int*)ga,
                (__attribute__((address_space(3))) unsigned int*)(&Ks[buf][(w * 16 + s * 4) * 128]),
                16, 0, 0);
        }
    };

    ushort8v va[2], vb[2];
    auto load_v = [&](int kt2) {
        const unsigned short* vsrc = vm + bbase + (size_t)(kt2 * 64 + vk0) * DD + vd8 * 8;
        va[0] = *(const ushort8v*)(vsrc);
        vb[0] = *(const ushort8v*)(vsrc + DD);
        va[1] = *(const ushort8v*)(vsrc + 64);
        vb[1] = *(const ushort8v*)(vsrc + DD + 64);
    };
    auto write_v = [&]() {
#pragma unroll
        for (int i = 0; i < 2; ++i)
#pragma unroll
            for (int j = 0; j < 8; ++j) {
                int d = (vd8 + 8 * i) * 8 + j;
                int swz = (vk0 >> 3) ^ ((d >> 3) & 7);
                unsigned int pack = (unsigned int)va[i][j] | ((unsigned int)vb[i][j] << 16);
                *(unsigned int*)&Vt[d * 64 + swz * 8 + (vk0 & 7)] = pack;
            }
    };

    // --- prologue: tile 0 ---
    stage_k(0, 0);
    load_v(0);
    write_v();
    __syncthreads();

    int cbase = (l15 >> 2) & 3;
    int gsw = (g ^ (l15 & 3)) * 8;

    for (int kt = 0; kt < nt; ++kt) {
        int cur = kt & 1;
        bool pref = (kt + 1 < nt);
        if (pref) {
            stage_k(kt + 1, cur ^ 1);
            load_v(kt + 1);
        }

        // ---- S^T = K * Q^T (C: col=l15=q, row=g*4+r=k within kg) ----
        f32x4 s_[4] = {};
#pragma unroll
        for (int c = 0; c < 4; ++c) {
            int coff = ((c ^ cbase) * 32) + gsw;
#pragma unroll
            for (int kg = 0; kg < 4; ++kg) {
                bf16x8 kf = *(const bf16x8*)&Ks[cur][(kg * 16 + l15) * 128 + coff];
                s_[kg] = __builtin_amdgcn_mfma_f32_16x16x32_bf16(kf, qf[c], s_[kg], 0, 0, 0);
            }
        }

        // ---- mask + online softmax (T13 defer-max) ----
        float p[16];
        float mt = -INFINITY;
        int qrel = w * 16 + l15;
        bool diag = (kt == qt);
#pragma unroll
        for (int kg = 0; kg < 4; ++kg)
#pragma unroll
            for (int r = 0; r < 4; ++r) {
                float sv = s_[kg][r] * SCALE;
                if (diag && (kg * 16 + g * 4 + r > qrel)) sv = -INFINITY;
                p[kg * 4 + r] = sv;
                mt = fmaxf(mt, sv);
            }
        mt = fmaxf(mt, __shfl_xor(mt, 16));
        mt = fmaxf(mt, __shfl_xor(mt, 32));
        if (!__all(mt - m_ <= 8.0f)) {
            float mnew = fmaxf(m_, mt);
            float alpha = __expf(m_ - mnew);
            float ar[4];
#pragma unroll
            for (int r = 0; r < 4; ++r) ar[r] = __shfl(alpha, 4 * g + r);
#pragma unroll
            for (int dg = 0; dg < 8; ++dg)
#pragma unroll
                for (int r = 0; r < 4; ++r) acc_o[dg][r] *= ar[r];
            l_ *= alpha;
            m_ = mnew;
        }
        float ps = 0.0f;
#pragma unroll
        for (int n = 0; n < 16; ++n) {
            p[n] = __expf(p[n] - m_);
            ps += p[n];
        }
        ps += __shfl_xor(ps, 16);
        ps += __shfl_xor(ps, 32);
        l_ += ps;

        // ---- PV in two k-halves (Ps buffer reused; same-wave in-order DS) ----
#pragma unroll
        for (int ks = 0; ks < 2; ++ks) {
#pragma unroll
            for (int kh = 0; kh < 2; ++kh) {
                int kg = 2 * ks + kh;
                union { __bf16 hv[4]; uint2 u2; } pk;
#pragma unroll
                for (int r = 0; r < 4; ++r) pk.hv[r] = (__bf16)p[kg * 4 + r];
                *(uint2*)&Ps[w][l15 * 40 + kh * 16 + g * 4] = pk.u2;
            }
            bf16x8 pf = *(const bf16x8*)&Ps[w][l15 * 40 + g * 8];
#pragma unroll
            for (int dg = 0; dg < 8; ++dg) {
                int d = dg * 16 + l15;
                int swz = (ks * 4 + g) ^ ((d >> 3) & 7);
                bf16x8 vf = *(const bf16x8*)&Vt[d * 64 + swz * 8];
                acc_o[dg] = __builtin_amdgcn_mfma_f32_16x16x32_bf16(pf, vf, acc_o[dg], 0, 0, 0);
            }
        }

        __syncthreads();           // all waves done reading Vt/Ks[cur]; prefetch drained
        if (pref) write_v();       // regs -> Vt for tile kt+1
        __syncthreads();           // Vt ready
    }

    // ---- epilogue: O / lsum -> bf16 (O row q' = g*4+r, col d = dg*16+l15) ----
    float lr[4];
#pragma unroll
    for (int r = 0; r < 4; ++r) lr[r] = 1.0f / __shfl(l_, 4 * g + r);
#pragma unroll
    for (int dg = 0; dg < 8; ++dg)
#pragma unroll
        for (int r = 0; r < 4; ++r) {
            int qrow2 = q0 + w * 16 + g * 4 + r;
            om[bbase + (size_t)qrow2 * DD + dg * 16 + l15] =
                f2bf(acc_o[dg][r] * lr[r]);
        }
}

// ---------------------------------------------------------------------------
extern "C" void kernel_launch(void* const* d_in, const int* in_sizes, int n_in,
                              void* d_out, int out_size, void* d_ws, size_t ws_size,
                              hipStream_t stream) {
    const float* x  = (const float*)d_in[0];
    const float* Wq = (const float*)d_in[1];
    const float* Wk = (const float*)d_in[2];
    const float* Wv = (const float*)d_in[3];
    const float* Wo = (const float*)d_in[4];
    float* out = (float*)d_out;

    char* ws = (char*)d_ws;
    const size_t MD = (size_t)MM * DD;
    const size_t WN = (size_t)DD * DD;
    unsigned short* qb   = (unsigned short*)(ws);
    unsigned short* kb   = (unsigned short*)(ws + 2 * MD);
    unsigned short* vb   = (unsigned short*)(ws + 4 * MD);
    unsigned short* ctxb = (unsigned short*)(ws + 6 * MD);
    unsigned short* xb   = (unsigned short*)(ws + 8 * MD);
    unsigned short* wqb  = (unsigned short*)(ws + 10 * MD);
    unsigned short* wkb  = (unsigned short*)(ws + 10 * MD + 2 * WN);
    unsigned short* wvb  = (unsigned short*)(ws + 10 * MD + 4 * WN);
    unsigned short* wob  = (unsigned short*)(ws + 10 * MD + 6 * WN);
    float* cost = (float*)(ws + 10 * MD + 8 * WN);
    float* sint = cost + SS * 64;

    cast_f32_bf16<<<(int)(MD / 4 / 256), 256, 0, stream>>>(x, xb, (int)(MD / 4));
    cast_f32_bf16<<<(int)(WN / 4 / 256), 256, 0, stream>>>(Wq, wqb, (int)(WN / 4));
    cast_f32_bf16<<<(int)(WN / 4 / 256), 256, 0, stream>>>(Wk, wkb, (int)(WN / 4));
    cast_f32_bf16<<<(int)(WN / 4 / 256), 256, 0, stream>>>(Wv, wvb, (int)(WN / 4));
    cast_f32_bf16<<<(int)(WN / 4 / 256), 256, 0, stream>>>(Wo, wob, (int)(WN / 4));

    rope_table_kernel<<<SS, 64, 0, stream>>>(cost, sint);

    dim3 gemm_grid(DD / 128, MM / 128);
    gemm_bf16<false><<<gemm_grid, 256, 0, stream>>>(xb, wqb, qb, MM, DD, DD);
    gemm_bf16<false><<<gemm_grid, 256, 0, stream>>>(xb, wkb, kb, MM, DD, DD);
    gemm_bf16<false><<<gemm_grid, 256, 0, stream>>>(xb, wvb, vb, MM, DD, DD);

    rope_apply_kernel<<<MM * HH * 16 / 256, 256, 0, stream>>>(qb, cost, sint);
    rope_apply_kernel<<<MM * HH * 16 / 256, 256, 0, stream>>>(kb, cost, sint);

    mfma_attn<<<dim3(SS / 64, HH, BB), 256, 0, stream>>>(qb, kb, vb, ctxb);

    gemm_bf16<true><<<gemm_grid, 256, 0, stream>>>(ctxb, wob, out, MM, DD, DD);
}

// Round 5
// 412.911 us; speedup vs baseline: 6.9748x; 1.2521x over previous
//
#include <hip/hip_runtime.h>
#include <hip/hip_bf16.h>
#include <math.h>

// Problem constants (B=2, S=2048, D=2048, H=16, hd=128)
#define BB 2
#define SS 2048
#define DD 2048
#define HH 16
#define HD 128
#define MM (BB * SS)                 // 4096 rows
#define SCALE 0.08838834764831845f  // 1/sqrt(128)

typedef __attribute__((ext_vector_type(8))) __bf16 bf16x8;
typedef __attribute__((ext_vector_type(4))) float f32x4;
typedef __attribute__((ext_vector_type(8))) unsigned short ushort8v;

__device__ __forceinline__ float bf2f(unsigned short u) {
    union { unsigned int u; float f; } x;
    x.u = ((unsigned int)u) << 16;
    return x.f;
}
__device__ __forceinline__ unsigned short f2bf(float f) {
    union { float f; unsigned int u; } x;
    x.f = f;
    unsigned int r = x.u + 0x7FFFu + ((x.u >> 16) & 1u);  // RNE (finite inputs)
    return (unsigned short)(r >> 16);
}

// ---------------------------------------------------------------------------
// fp32 -> bf16 cast, float4-vectorized
// ---------------------------------------------------------------------------
__global__ __launch_bounds__(256) void cast_f32_bf16(const float* __restrict__ src,
                                                     unsigned short* __restrict__ dst,
                                                     int n4) {
    int i = blockIdx.x * 256 + threadIdx.x;
    if (i >= n4) return;
    float4 v = ((const float4*)src)[i];
    ushort4 o;
    o.x = f2bf(v.x); o.y = f2bf(v.y); o.z = f2bf(v.z); o.w = f2bf(v.w);
    ((ushort4*)dst)[i] = o;
}

// ---------------------------------------------------------------------------
// RoPE cos/sin table (fp32): table[s][i], i<64. angle = s * 10000^(-2i/128)
// ---------------------------------------------------------------------------
__global__ __launch_bounds__(64) void rope_table_kernel(float* __restrict__ cost,
                                                        float* __restrict__ sint) {
    int s = blockIdx.x;
    int i = threadIdx.x;  // 0..63
    float inv = powf(10000.0f, -((float)(2 * i) / 128.0f));
    float ang = (float)s * inv;
    cost[s * 64 + i] = cosf(ang);
    sint[s * 64 + i] = sinf(ang);
}

// ---------------------------------------------------------------------------
// bf16 MFMA GEMM body (m97 structure) shared by the two GEMM kernels below.
// 128x128 tile, BK=32, 256 threads = 4 waves (2x2), 4x4 frags 16x16x32.
// ---------------------------------------------------------------------------
#define GEMM_BODY(A_, W_, m0_, n0_, K_, ACC_)                                      \
    for (int k0 = 0; k0 < (K_); k0 += 32) {                                        \
        __syncthreads();                                                           \
        _Pragma("unroll")                                                          \
        for (int i = 0; i < 2; ++i) {                                              \
            int c = 2 * w + i;                                                     \
            int row = c * 16 + (l >> 2);                                           \
            const unsigned short* ga = (A_) + (size_t)((m0_) + row) * (K_) + k0 + (l & 3) * 8; \
            __builtin_amdgcn_global_load_lds(                                      \
                (const __attribute__((address_space(1))) unsigned int*)ga,         \
                (__attribute__((address_space(3))) unsigned int*)(As + c * 512),   \
                16, 0, 0);                                                         \
            const unsigned short* gb = (W_) + (size_t)((n0_) + row) * (K_) + k0 + (l & 3) * 8; \
            __builtin_amdgcn_global_load_lds(                                      \
                (const __attribute__((address_space(1))) unsigned int*)gb,         \
                (__attribute__((address_space(3))) unsigned int*)(Bs + c * 512),   \
                16, 0, 0);                                                         \
        }                                                                          \
        __syncthreads();                                                           \
        bf16x8 af[4], bfr[4];                                                      \
        _Pragma("unroll")                                                          \
        for (int i = 0; i < 4; ++i) {                                              \
            af[i]  = *(const bf16x8*)&As[(wr + i * 16 + rlane) * 32 + g * 8];      \
            bfr[i] = *(const bf16x8*)&Bs[(wc + i * 16 + rlane) * 32 + g * 8];      \
        }                                                                          \
        _Pragma("unroll")                                                          \
        for (int i = 0; i < 4; ++i)                                                \
            _Pragma("unroll")                                                      \
            for (int j = 0; j < 4; ++j)                                            \
                ACC_[i][j] = __builtin_amdgcn_mfma_f32_16x16x32_bf16(af[i], bfr[j], ACC_[i][j], 0, 0, 0); \
    }

// Fused QKV projection GEMM: A = xb [4096,2048], Wc = [6144,2048] (Wq;Wk;Wv),
// output split into qb/kb/vb (contiguous, MD elements apart). Grid (48,32).
__global__ __launch_bounds__(256) void gemm_qkv(const unsigned short* __restrict__ A,
                                                const unsigned short* __restrict__ Wc,
                                                unsigned short* __restrict__ qkv) {
    __shared__ unsigned short As[128 * 32];
    __shared__ unsigned short Bs[128 * 32];
    int t = threadIdx.x, w = t >> 6, l = t & 63;
    int rlane = l & 15, g = l >> 4;
    // T1 chunked XCD swizzle (nwg = 1536, 1536/8 = 192)
    int flat = (int)blockIdx.y * 48 + (int)blockIdx.x;
    int swz = (flat & 7) * 192 + (flat >> 3);
    int n0 = (swz % 48) * 128;
    int m0 = (swz / 48) * 128;
    int wr = (w >> 1) * 64, wc = (w & 1) * 64;
    f32x4 acc[4][4] = {};
    GEMM_BODY(A, Wc, m0, n0, 2048, acc)
    unsigned short* base = qkv + (size_t)(n0 >> 11) * ((size_t)MM * DD);
    int nc0 = n0 & 2047;
#pragma unroll
    for (int i = 0; i < 4; ++i)
#pragma unroll
        for (int r = 0; r < 4; ++r) {
            int row = m0 + wr + i * 16 + g * 4 + r;
#pragma unroll
            for (int j = 0; j < 4; ++j) {
                int col = nc0 + wc + j * 16 + rlane;
                base[(size_t)row * DD + col] = f2bf(acc[i][j][r]);
            }
        }
}

// Output projection GEMM: C[4096,2048] f32 = ctx * Wo^T. Grid (16,32).
__global__ __launch_bounds__(256) void gemm_out(const unsigned short* __restrict__ A,
                                                const unsigned short* __restrict__ W,
                                                float* __restrict__ C) {
    __shared__ unsigned short As[128 * 32];
    __shared__ unsigned short Bs[128 * 32];
    int t = threadIdx.x, w = t >> 6, l = t & 63;
    int rlane = l & 15, g = l >> 4;
    // T1 chunked XCD swizzle (nwg = 512, 512/8 = 64)
    int flat = (int)blockIdx.y * 16 + (int)blockIdx.x;
    int swz = (flat & 7) * 64 + (flat >> 3);
    int n0 = (swz % 16) * 128;
    int m0 = (swz / 16) * 128;
    int wr = (w >> 1) * 64, wc = (w & 1) * 64;
    f32x4 acc[4][4] = {};
    GEMM_BODY(A, W, m0, n0, 2048, acc)
#pragma unroll
    for (int i = 0; i < 4; ++i)
#pragma unroll
        for (int r = 0; r < 4; ++r) {
            int row = m0 + wr + i * 16 + g * 4 + r;
#pragma unroll
            for (int j = 0; j < 4; ++j) {
                int col = n0 + wc + j * 16 + rlane;
                C[(size_t)row * DD + col] = acc[i][j][r];
            }
        }
}

// ---------------------------------------------------------------------------
// RoPE in-place on bf16 [rows, D] (q and k processed in one launch: rows=2*MM).
// ---------------------------------------------------------------------------
__global__ __launch_bounds__(256) void rope_apply_kernel(unsigned short* __restrict__ arr,
                                                         const float* __restrict__ cost,
                                                         const float* __restrict__ sint) {
    int idx = blockIdx.x * 256 + threadIdx.x;
    int i4 = (idx & 15) * 4;
    int h = (idx >> 4) & 15;
    int row = idx >> 8;
    int s = row & (SS - 1);
    float4 c  = *(const float4*)&cost[s * 64 + i4];
    float4 sn = *(const float4*)&sint[s * 64 + i4];
    size_t p0 = (size_t)row * DD + h * HD + i4;
    ushort4 lo = *(ushort4*)&arr[p0];
    ushort4 hi = *(ushort4*)&arr[p0 + 64];
    ushort4 olo, ohi;
    olo.x = f2bf(bf2f(lo.x) * c.x - bf2f(hi.x) * sn.x);
    olo.y = f2bf(bf2f(lo.y) * c.y - bf2f(hi.y) * sn.y);
    olo.z = f2bf(bf2f(lo.z) * c.z - bf2f(hi.z) * sn.z);
    olo.w = f2bf(bf2f(lo.w) * c.w - bf2f(hi.w) * sn.w);
    ohi.x = f2bf(bf2f(hi.x) * c.x + bf2f(lo.x) * sn.x);
    ohi.y = f2bf(bf2f(hi.y) * c.y + bf2f(lo.y) * sn.y);
    ohi.z = f2bf(bf2f(hi.z) * c.z + bf2f(lo.z) * sn.z);
    ohi.w = f2bf(bf2f(hi.w) * c.w + bf2f(lo.w) * sn.w);
    *(ushort4*)&arr[p0] = olo;
    *(ushort4*)&arr[p0 + 64] = ohi;
}

// ---------------------------------------------------------------------------
// MFMA causal flash attention v3.
// Grid (16, H, B) = 512 blocks (exactly 2/CU), 256 threads = 4 waves.
// Each block processes q-tiles (31 - j) then (j): 33 k-iters per block, uniform.
// Wave = 16 q rows. KV tile = 64. One barrier per iteration:
//   K double-buffered LDS (global_load_lds, both-sides swizzle),
//   Vt double-buffered (T14: global->reg at iter top, reg->LDS after PV).
// Online softmax with T13 defer-max (THR=8).
// ---------------------------------------------------------------------------
__global__ __launch_bounds__(256, 2) void mfma_attn(const unsigned short* __restrict__ qm,
                                                    const unsigned short* __restrict__ km,
                                                    const unsigned short* __restrict__ vm,
                                                    unsigned short* __restrict__ om) {
    __shared__ unsigned short Ks[2][64 * 128];   // 2 x 16 KB, swizzled layout
    __shared__ unsigned short Vt[2][128 * 64];   // 2 x 16 KB, slot-swizzled [d][k]
    __shared__ unsigned short Ps[4][16 * 40];    // 5 KB

    int t = threadIdx.x;
    int w = t >> 6;
    int l = t & 63;
    int l15 = l & 15;
    int g = l >> 4;

    int pj = blockIdx.x;   // 0..15
    int h = blockIdx.y;
    int b = blockIdx.z;
    size_t bbase = (size_t)b * SS * DD + (size_t)h * HD;

    int vk0 = 2 * (t >> 3);   // 0..62 even
    int vd8 = t & 7;
    int cbase = (l15 >> 2) & 3;
    int gsw = (g ^ (l15 & 3)) * 8;

    auto stage_k = [&](int kt2, int buf) {
#pragma unroll
        for (int s = 0; s < 4; ++s) {
            int row = w * 16 + s * 4 + (l >> 4);
            int c = ((l >> 2) & 3) ^ s;          // inverse swizzle on global src
            int gg = (l & 3) ^ (l >> 4);
            const unsigned short* ga = km + bbase +
                (size_t)(kt2 * 64 + row) * DD + c * 32 + gg * 8;
            __builtin_amdgcn_global_load_lds(
                (const __attribute__((address_space(1))) unsigned int*)ga,
                (__attribute__((address_space(3))) unsigned int*)(&Ks[buf][(w * 16 + s * 4) * 128]),
                16, 0, 0);
        }
    };

    ushort8v va[2], vb[2];
    auto load_v = [&](int kt2) {
        const unsigned short* vsrc = vm + bbase + (size_t)(kt2 * 64 + vk0) * DD + vd8 * 8;
        va[0] = *(const ushort8v*)(vsrc);
        vb[0] = *(const ushort8v*)(vsrc + DD);
        va[1] = *(const ushort8v*)(vsrc + 64);
        vb[1] = *(const ushort8v*)(vsrc + DD + 64);
    };
    auto write_v = [&](int buf) {
#pragma unroll
        for (int i = 0; i < 2; ++i)
#pragma unroll
            for (int j = 0; j < 8; ++j) {
                int d = (vd8 + 8 * i) * 8 + j;
                int swz = (vk0 >> 3) ^ ((d >> 3) & 7);
                unsigned int pack = (unsigned int)va[i][j] | ((unsigned int)vb[i][j] << 16);
                *(unsigned int*)&Vt[buf][d * 64 + swz * 8 + (vk0 & 7)] = pack;
            }
    };

#pragma unroll 1
    for (int half = 0; half < 2; ++half) {
        int qt = half ? pj : (31 - pj);
        int q0 = qt * 64;

        // Q fragments (B-operand): wave w rows q0+w*16+l15, chunk c*32 + g*8
        bf16x8 qf[4];
        {
            int qrow = q0 + w * 16 + l15;
#pragma unroll
            for (int c = 0; c < 4; ++c)
                qf[c] = *(const bf16x8*)(qm + bbase + (size_t)qrow * DD + c * 32 + g * 8);
        }

        f32x4 acc_o[8] = {};
        float m_ = -INFINITY;
        float l_ = 0.0f;
        int nt = qt + 1;

        // prologue: tile 0 into buffer 0 (prior-half readers already synced
        // by the final in-loop barrier; epilogue does no LDS access)
        stage_k(0, 0);
        load_v(0);
        write_v(0);
        __syncthreads();

        for (int kt = 0; kt < nt; ++kt) {
            int cur = kt & 1;
            bool pref = (kt + 1 < nt);
            if (pref) {
                stage_k(kt + 1, cur ^ 1);
                load_v(kt + 1);
            }

            // ---- S^T = K * Q^T (C: col=l15=q, row=g*4+r=k within kg) ----
            f32x4 s_[4] = {};
#pragma unroll
            for (int c = 0; c < 4; ++c) {
                int coff = ((c ^ cbase) * 32) + gsw;
#pragma unroll
                for (int kg = 0; kg < 4; ++kg) {
                    bf16x8 kf = *(const bf16x8*)&Ks[cur][(kg * 16 + l15) * 128 + coff];
                    s_[kg] = __builtin_amdgcn_mfma_f32_16x16x32_bf16(kf, qf[c], s_[kg], 0, 0, 0);
                }
            }

            // ---- mask + online softmax (T13 defer-max) ----
            float p[16];
            int qrel = w * 16 + l15;
            bool diag = (kt == qt);
#pragma unroll
            for (int kg = 0; kg < 4; ++kg)
#pragma unroll
                for (int r = 0; r < 4; ++r) {
                    float sv = s_[kg][r] * SCALE;
                    if (diag && (kg * 16 + g * 4 + r > qrel)) sv = -INFINITY;
                    p[kg * 4 + r] = sv;
                }
            // pairwise-tree max over 16 in-lane values
            float mt01 = fmaxf(fmaxf(p[0], p[1]), fmaxf(p[2], p[3]));
            float mt23 = fmaxf(fmaxf(p[4], p[5]), fmaxf(p[6], p[7]));
            float mt45 = fmaxf(fmaxf(p[8], p[9]), fmaxf(p[10], p[11]));
            float mt67 = fmaxf(fmaxf(p[12], p[13]), fmaxf(p[14], p[15]));
            float mt = fmaxf(fmaxf(mt01, mt23), fmaxf(mt45, mt67));
            mt = fmaxf(mt, __shfl_xor(mt, 16));
            mt = fmaxf(mt, __shfl_xor(mt, 32));
            if (!__all(mt - m_ <= 8.0f)) {
                float mnew = fmaxf(m_, mt);
                float alpha = __expf(m_ - mnew);
                float ar[4];
#pragma unroll
                for (int r = 0; r < 4; ++r) ar[r] = __shfl(alpha, 4 * g + r);
#pragma unroll
                for (int dg = 0; dg < 8; ++dg)
#pragma unroll
                    for (int r = 0; r < 4; ++r) acc_o[dg][r] *= ar[r];
                l_ *= alpha;
                m_ = mnew;
            }
            float ps = 0.0f;
#pragma unroll
            for (int n = 0; n < 16; ++n) {
                p[n] = __expf(p[n] - m_);
                ps += p[n];
            }
            ps += __shfl_xor(ps, 16);
            ps += __shfl_xor(ps, 32);
            l_ += ps;

            // ---- PV in two k-halves (Ps reused; same-wave in-order DS) ----
#pragma unroll
            for (int ks = 0; ks < 2; ++ks) {
#pragma unroll
                for (int kh = 0; kh < 2; ++kh) {
                    int kg = 2 * ks + kh;
                    union { __bf16 hv[4]; uint2 u2; } pk;
#pragma unroll
                    for (int r = 0; r < 4; ++r) pk.hv[r] = (__bf16)p[kg * 4 + r];
                    *(uint2*)&Ps[w][l15 * 40 + kh * 16 + g * 4] = pk.u2;
                }
                bf16x8 pf = *(const bf16x8*)&Ps[w][l15 * 40 + g * 8];
#pragma unroll
                for (int dg = 0; dg < 8; ++dg) {
                    int d = dg * 16 + l15;
                    int swz = (ks * 4 + g) ^ ((d >> 3) & 7);
                    bf16x8 vf = *(const bf16x8*)&Vt[cur][d * 64 + swz * 8];
                    acc_o[dg] = __builtin_amdgcn_mfma_f32_16x16x32_bf16(pf, vf, acc_o[dg], 0, 0, 0);
                }
            }

            // write next tile's V into the idle buffer (read by nobody this iter)
            if (pref) write_v(cur ^ 1);
            __syncthreads();   // one barrier per iter: V/K buffers ready, reads done
        }

        // ---- epilogue: O / lsum -> bf16 (global stores only, no LDS) ----
        float lr[4];
#pragma unroll
        for (int r = 0; r < 4; ++r) lr[r] = 1.0f / __shfl(l_, 4 * g + r);
#pragma unroll
        for (int dg = 0; dg < 8; ++dg)
#pragma unroll
            for (int r = 0; r < 4; ++r) {
                int qrow2 = q0 + w * 16 + g * 4 + r;
                om[bbase + (size_t)qrow2 * DD + dg * 16 + l15] =
                    f2bf(acc_o[dg][r] * lr[r]);
            }
    }
}

// ---------------------------------------------------------------------------
extern "C" void kernel_launch(void* const* d_in, const int* in_sizes, int n_in,
                              void* d_out, int out_size, void* d_ws, size_t ws_size,
                              hipStream_t stream) {
    const float* x  = (const float*)d_in[0];
    const float* Wq = (const float*)d_in[1];
    const float* Wk = (const float*)d_in[2];
    const float* Wv = (const float*)d_in[3];
    const float* Wo = (const float*)d_in[4];
    float* out = (float*)d_out;

    char* ws = (char*)d_ws;
    const size_t MD = (size_t)MM * DD;
    const size_t WN = (size_t)DD * DD;
    unsigned short* qb   = (unsigned short*)(ws);            // q,k,v contiguous
    unsigned short* kb   = (unsigned short*)(ws + 2 * MD);
    unsigned short* vb   = (unsigned short*)(ws + 4 * MD);
    unsigned short* ctxb = (unsigned short*)(ws + 6 * MD);
    unsigned short* xb   = (unsigned short*)(ws + 8 * MD);
    unsigned short* wqb  = (unsigned short*)(ws + 10 * MD);  // Wq,Wk,Wv contiguous
    unsigned short* wkb  = (unsigned short*)(ws + 10 * MD + 2 * WN);
    unsigned short* wvb  = (unsigned short*)(ws + 10 * MD + 4 * WN);
    unsigned short* wob  = (unsigned short*)(ws + 10 * MD + 6 * WN);
    float* cost = (float*)(ws + 10 * MD + 8 * WN);
    float* sint = cost + SS * 64;

    cast_f32_bf16<<<(int)(MD / 4 / 256), 256, 0, stream>>>(x, xb, (int)(MD / 4));
    cast_f32_bf16<<<(int)(WN / 4 / 256), 256, 0, stream>>>(Wq, wqb, (int)(WN / 4));
    cast_f32_bf16<<<(int)(WN / 4 / 256), 256, 0, stream>>>(Wk, wkb, (int)(WN / 4));
    cast_f32_bf16<<<(int)(WN / 4 / 256), 256, 0, stream>>>(Wv, wvb, (int)(WN / 4));
    cast_f32_bf16<<<(int)(WN / 4 / 256), 256, 0, stream>>>(Wo, wob, (int)(WN / 4));

    rope_table_kernel<<<SS, 64, 0, stream>>>(cost, sint);

    // fused QKV projection: 1536 blocks
    gemm_qkv<<<dim3(48, 32), 256, 0, stream>>>(xb, wqb, qb);

    // RoPE over q and k in one launch (contiguous buffers)
    rope_apply_kernel<<<2 * MM * HH * 16 / 256, 256, 0, stream>>>(qb, cost, sint);

    mfma_attn<<<dim3(16, HH, BB), 256, 0, stream>>>(qb, kb, vb, ctxb);

    gemm_out<<<dim3(16, 32), 256, 0, stream>>>(ctxb, wob, out);
}

// Round 8
// 402.922 us; speedup vs baseline: 7.1477x; 1.0248x over previous
//
#include <hip/hip_runtime.h>
#include <hip/hip_bf16.h>
#include <math.h>

// Problem constants (B=2, S=2048, D=2048, H=16, hd=128)
#define BB 2
#define SS 2048
#define DD 2048
#define HH 16
#define HD 128
#define MM (BB * SS)                 // 4096 rows
#define SCALE 0.08838834764831845f  // 1/sqrt(128)

typedef __attribute__((ext_vector_type(8))) __bf16 bf16x8;
typedef __attribute__((ext_vector_type(4))) float f32x4;
typedef __attribute__((ext_vector_type(8))) unsigned short ushort8v;

__device__ __forceinline__ float bf2f(unsigned short u) {
    union { unsigned int u; float f; } x;
    x.u = ((unsigned int)u) << 16;
    return x.f;
}
__device__ __forceinline__ unsigned short f2bf(float f) {
    union { float f; unsigned int u; } x;
    x.f = f;
    unsigned int r = x.u + 0x7FFFu + ((x.u >> 16) & 1u);  // RNE (finite inputs)
    return (unsigned short)(r >> 16);
}

// ---------------------------------------------------------------------------
// Fused fp32 -> bf16 cast for x (8192 blocks) + Wq/Wk/Wv/Wo (4 x 4096 blocks).
// Weight destinations are contiguous starting at wqb.
// ---------------------------------------------------------------------------
__global__ __launch_bounds__(256) void cast_all(const float* __restrict__ x,
                                                const float* __restrict__ Wq,
                                                const float* __restrict__ Wk,
                                                const float* __restrict__ Wv,
                                                const float* __restrict__ Wo,
                                                unsigned short* __restrict__ xb,
                                                unsigned short* __restrict__ wqb) {
    int bid = blockIdx.x;
    const float* src;
    unsigned short* dst;
    int idx;
    if (bid < 8192) {                 // x: MD/4 = 2,097,152 float4s
        src = x; dst = xb;
        idx = bid * 256 + threadIdx.x;
    } else {
        int seg = (bid - 8192) >> 12;             // 0..3
        idx = ((bid - 8192) & 4095) * 256 + threadIdx.x;
        src = (seg == 0) ? Wq : (seg == 1) ? Wk : (seg == 2) ? Wv : Wo;
        dst = wqb + (size_t)seg * ((size_t)DD * DD);
    }
    float4 v = ((const float4*)src)[idx];
    ushort4 o;
    o.x = f2bf(v.x); o.y = f2bf(v.y); o.z = f2bf(v.z); o.w = f2bf(v.w);
    ((ushort4*)dst)[idx] = o;
}

// ---------------------------------------------------------------------------
// RoPE cos/sin table (fp32): table[s][i], i<64. angle = s * 10000^(-2i/128)
// ---------------------------------------------------------------------------
__global__ __launch_bounds__(64) void rope_table_kernel(float* __restrict__ cost,
                                                        float* __restrict__ sint) {
    int s = blockIdx.x;
    int i = threadIdx.x;  // 0..63
    float inv = powf(10000.0f, -((float)(2 * i) / 128.0f));
    float ang = (float)s * inv;
    cost[s * 64 + i] = cosf(ang);
    sint[s * 64 + i] = sinf(ang);
}

// ---------------------------------------------------------------------------
// bf16 MFMA GEMM body (m97 structure) shared by the two GEMM kernels below.
// 128x128 tile, BK=32, 256 threads = 4 waves (2x2), 4x4 frags 16x16x32.
// ---------------------------------------------------------------------------
#define GEMM_BODY(A_, W_, m0_, n0_, K_, ACC_)                                      \
    for (int k0 = 0; k0 < (K_); k0 += 32) {                                        \
        __syncthreads();                                                           \
        _Pragma("unroll")                                                          \
        for (int i = 0; i < 2; ++i) {                                              \
            int c = 2 * w + i;                                                     \
            int row = c * 16 + (l >> 2);                                           \
            const unsigned short* ga = (A_) + (size_t)((m0_) + row) * (K_) + k0 + (l & 3) * 8; \
            __builtin_amdgcn_global_load_lds(                                      \
                (const __attribute__((address_space(1))) unsigned int*)ga,         \
                (__attribute__((address_space(3))) unsigned int*)(As + c * 512),   \
                16, 0, 0);                                                         \
            const unsigned short* gb = (W_) + (size_t)((n0_) + row) * (K_) + k0 + (l & 3) * 8; \
            __builtin_amdgcn_global_load_lds(                                      \
                (const __attribute__((address_space(1))) unsigned int*)gb,         \
                (__attribute__((address_space(3))) unsigned int*)(Bs + c * 512),   \
                16, 0, 0);                                                         \
        }                                                                          \
        __syncthreads();                                                           \
        bf16x8 af[4], bfr[4];                                                      \
        _Pragma("unroll")                                                          \
        for (int i = 0; i < 4; ++i) {                                              \
            af[i]  = *(const bf16x8*)&As[(wr + i * 16 + rlane) * 32 + g * 8];      \
            bfr[i] = *(const bf16x8*)&Bs[(wc + i * 16 + rlane) * 32 + g * 8];      \
        }                                                                          \
        _Pragma("unroll")                                                          \
        for (int i = 0; i < 4; ++i)                                                \
            _Pragma("unroll")                                                      \
            for (int j = 0; j < 4; ++j)                                            \
                ACC_[i][j] = __builtin_amdgcn_mfma_f32_16x16x32_bf16(af[i], bfr[j], ACC_[i][j], 0, 0, 0); \
    }

// Fused QKV projection GEMM: A = xb [4096,2048], Wc = [6144,2048] (Wq;Wk;Wv),
// output split into qb/kb/vb (contiguous, MD elements apart). Grid (48,32).
__global__ __launch_bounds__(256) void gemm_qkv(const unsigned short* __restrict__ A,
                                                const unsigned short* __restrict__ Wc,
                                                unsigned short* __restrict__ qkv) {
    __shared__ unsigned short As[128 * 32];
    __shared__ unsigned short Bs[128 * 32];
    int t = threadIdx.x, w = t >> 6, l = t & 63;
    int rlane = l & 15, g = l >> 4;
    // T1 chunked XCD swizzle (nwg = 1536, 1536/8 = 192)
    int flat = (int)blockIdx.y * 48 + (int)blockIdx.x;
    int swz = (flat & 7) * 192 + (flat >> 3);
    int n0 = (swz % 48) * 128;
    int m0 = (swz / 48) * 128;
    int wr = (w >> 1) * 64, wc = (w & 1) * 64;
    f32x4 acc[4][4] = {};
    GEMM_BODY(A, Wc, m0, n0, 2048, acc)
    unsigned short* base = qkv + (size_t)(n0 >> 11) * ((size_t)MM * DD);
    int nc0 = n0 & 2047;
#pragma unroll
    for (int i = 0; i < 4; ++i)
#pragma unroll
        for (int r = 0; r < 4; ++r) {
            int row = m0 + wr + i * 16 + g * 4 + r;
#pragma unroll
            for (int j = 0; j < 4; ++j) {
                int col = nc0 + wc + j * 16 + rlane;
                base[(size_t)row * DD + col] = f2bf(acc[i][j][r]);
            }
        }
}

// Output projection GEMM: C[4096,2048] f32 = ctx * Wo^T. Grid (16,32).
__global__ __launch_bounds__(256) void gemm_out(const unsigned short* __restrict__ A,
                                                const unsigned short* __restrict__ W,
                                                float* __restrict__ C) {
    __shared__ unsigned short As[128 * 32];
    __shared__ unsigned short Bs[128 * 32];
    int t = threadIdx.x, w = t >> 6, l = t & 63;
    int rlane = l & 15, g = l >> 4;
    // T1 chunked XCD swizzle (nwg = 512, 512/8 = 64)
    int flat = (int)blockIdx.y * 16 + (int)blockIdx.x;
    int swz = (flat & 7) * 64 + (flat >> 3);
    int n0 = (swz % 16) * 128;
    int m0 = (swz / 16) * 128;
    int wr = (w >> 1) * 64, wc = (w & 1) * 64;
    f32x4 acc[4][4] = {};
    GEMM_BODY(A, W, m0, n0, 2048, acc)
#pragma unroll
    for (int i = 0; i < 4; ++i)
#pragma unroll
        for (int r = 0; r < 4; ++r) {
            int row = m0 + wr + i * 16 + g * 4 + r;
#pragma unroll
            for (int j = 0; j < 4; ++j) {
                int col = n0 + wc + j * 16 + rlane;
                C[(size_t)row * DD + col] = acc[i][j][r];
            }
        }
}

// ---------------------------------------------------------------------------
// RoPE in-place on bf16 [rows, D] (q and k processed in one launch: rows=2*MM).
// ---------------------------------------------------------------------------
__global__ __launch_bounds__(256) void rope_apply_kernel(unsigned short* __restrict__ arr,
                                                         const float* __restrict__ cost,
                                                         const float* __restrict__ sint) {
    int idx = blockIdx.x * 256 + threadIdx.x;
    int i4 = (idx & 15) * 4;
    int h = (idx >> 4) & 15;
    int row = idx >> 8;
    int s = row & (SS - 1);
    float4 c  = *(const float4*)&cost[s * 64 + i4];
    float4 sn = *(const float4*)&sint[s * 64 + i4];
    size_t p0 = (size_t)row * DD + h * HD + i4;
    ushort4 lo = *(ushort4*)&arr[p0];
    ushort4 hi = *(ushort4*)&arr[p0 + 64];
    ushort4 olo, ohi;
    olo.x = f2bf(bf2f(lo.x) * c.x - bf2f(hi.x) * sn.x);
    olo.y = f2bf(bf2f(lo.y) * c.y - bf2f(hi.y) * sn.y);
    olo.z = f2bf(bf2f(lo.z) * c.z - bf2f(hi.z) * sn.z);
    olo.w = f2bf(bf2f(lo.w) * c.w - bf2f(hi.w) * sn.w);
    ohi.x = f2bf(bf2f(hi.x) * c.x + bf2f(lo.x) * sn.x);
    ohi.y = f2bf(bf2f(hi.y) * c.y + bf2f(lo.y) * sn.y);
    ohi.z = f2bf(bf2f(hi.z) * c.z + bf2f(lo.z) * sn.z);
    ohi.w = f2bf(bf2f(hi.w) * c.w + bf2f(lo.w) * sn.w);
    *(ushort4*)&arr[p0] = olo;
    *(ushort4*)&arr[p0 + 64] = ohi;
}

// ---------------------------------------------------------------------------
// MFMA causal flash attention v4.
// Grid (16, H, B) = 512 blocks, 256 threads = 4 waves. Block handles q-tiles
// (31-j) then (j): exactly 33 KV-iters per block (uniform). Wave = 16 q rows,
// KV tile = 64.
// K: double-buffered LDS (global_load_lds, both-sides swizzle) - full-iter slack.
// V: single Vt buffer (T14: global->reg at iter top; reg->LDS between the two
//    iter-end barriers). LDS total 54,272 B -> 3 blocks/CU.
// T5 setprio around MFMA clusters; T13 defer-max (THR=8).
// ---------------------------------------------------------------------------
__global__ __launch_bounds__(256, 3) void mfma_attn(const unsigned short* __restrict__ qm,
                                                    const unsigned short* __restrict__ km,
                                                    const unsigned short* __restrict__ vm,
                                                    unsigned short* __restrict__ om) {
    __shared__ unsigned short Ks[2][64 * 128];   // 2 x 16 KB, swizzled layout
    __shared__ unsigned short Vt[128 * 64];      // 16 KB, slot-swizzled [d][k]
    __shared__ unsigned short Ps[4][16 * 40];    // 5 KB

    int t = threadIdx.x;
    int w = t >> 6;
    int l = t & 63;
    int l15 = l & 15;
    int g = l >> 4;

    int pj = blockIdx.x;   // 0..15
    int h = blockIdx.y;
    int b = blockIdx.z;
    size_t bbase = (size_t)b * SS * DD + (size_t)h * HD;

    int vk0 = 2 * (t >> 3);   // 0..62 even
    int vd8 = t & 7;
    int cbase = (l15 >> 2) & 3;
    int gsw = (g ^ (l15 & 3)) * 8;

    auto stage_k = [&](int kt2, int buf) {
#pragma unroll
        for (int s = 0; s < 4; ++s) {
            int row = w * 16 + s * 4 + (l >> 4);
            int c = ((l >> 2) & 3) ^ s;          // inverse swizzle on global src
            int gg = (l & 3) ^ (l >> 4);
            const unsigned short* ga = km + bbase +
                (size_t)(kt2 * 64 + row) * DD + c * 32 + gg * 8;
            __builtin_amdgcn_global_load_lds(
                (const __attribute__((address_space(1))) unsigned int*)ga,
                (__attribute__((address_space(3))) unsigned int*)(&Ks[buf][(w * 16 + s * 4) * 128]),
                16, 0, 0);
        }
    };

    ushort8v va[2], vb[2];
    auto load_v = [&](int kt2) {
        const unsigned short* vsrc = vm + bbase + (size_t)(kt2 * 64 + vk0) * DD + vd8 * 8;
        va[0] = *(const ushort8v*)(vsrc);
        vb[0] = *(const ushort8v*)(vsrc + DD);
        va[1] = *(const ushort8v*)(vsrc + 64);
        vb[1] = *(const ushort8v*)(vsrc + DD + 64);
    };
    auto write_v = [&]() {
#pragma unroll
        for (int i = 0; i < 2; ++i)
#pragma unroll
            for (int j = 0; j < 8; ++j) {
                int d = (vd8 + 8 * i) * 8 + j;
                int swz = (vk0 >> 3) ^ ((d >> 3) & 7);
                unsigned int pack = (unsigned int)va[i][j] | ((unsigned int)vb[i][j] << 16);
                *(unsigned int*)&Vt[d * 64 + swz * 8 + (vk0 & 7)] = pack;
            }
    };

#pragma unroll 1
    for (int half = 0; half < 2; ++half) {
        int qt = half ? pj : (31 - pj);
        int q0 = qt * 64;

        // Q fragments (B-operand): wave w rows q0+w*16+l15, chunk c*32 + g*8
        bf16x8 qf[4];
        {
            int qrow = q0 + w * 16 + l15;
#pragma unroll
            for (int c = 0; c < 4; ++c)
                qf[c] = *(const bf16x8*)(qm + bbase + (size_t)qrow * DD + c * 32 + g * 8);
        }

        f32x4 acc_o[8] = {};
        float m_ = -INFINITY;
        float l_ = 0.0f;
        int nt = qt + 1;

        // prologue: tile 0 into K buffer 0 + Vt. (All waves passed the final
        // in-loop barrier of the previous half; epilogue does no LDS access.)
        stage_k(0, 0);
        load_v(0);
        write_v();           // waits its own loads (vmcnt), then LDS write
        __syncthreads();

        for (int kt = 0; kt < nt; ++kt) {
            int cur = kt & 1;
            bool pref = (kt + 1 < nt);
            if (pref) {
                stage_k(kt + 1, cur ^ 1);   // full-iteration DMA slack
                load_v(kt + 1);             // regs; consumed at iter end
            }

            // ---- S^T = K * Q^T (C: col=l15=q, row=g*4+r=k within kg) ----
            f32x4 s_[4] = {};
            __builtin_amdgcn_s_setprio(1);
#pragma unroll
            for (int c = 0; c < 4; ++c) {
                int coff = ((c ^ cbase) * 32) + gsw;
#pragma unroll
                for (int kg = 0; kg < 4; ++kg) {
                    bf16x8 kf = *(const bf16x8*)&Ks[cur][(kg * 16 + l15) * 128 + coff];
                    s_[kg] = __builtin_amdgcn_mfma_f32_16x16x32_bf16(kf, qf[c], s_[kg], 0, 0, 0);
                }
            }
            __builtin_amdgcn_s_setprio(0);

            // ---- mask + online softmax (T13 defer-max) ----
            float p[16];
            int qrel = w * 16 + l15;
            bool diag = (kt == qt);
#pragma unroll
            for (int kg = 0; kg < 4; ++kg)
#pragma unroll
                for (int r = 0; r < 4; ++r) {
                    float sv = s_[kg][r] * SCALE;
                    if (diag && (kg * 16 + g * 4 + r > qrel)) sv = -INFINITY;
                    p[kg * 4 + r] = sv;
                }
            float mt01 = fmaxf(fmaxf(p[0], p[1]), fmaxf(p[2], p[3]));
            float mt23 = fmaxf(fmaxf(p[4], p[5]), fmaxf(p[6], p[7]));
            float mt45 = fmaxf(fmaxf(p[8], p[9]), fmaxf(p[10], p[11]));
            float mt67 = fmaxf(fmaxf(p[12], p[13]), fmaxf(p[14], p[15]));
            float mt = fmaxf(fmaxf(mt01, mt23), fmaxf(mt45, mt67));
            mt = fmaxf(mt, __shfl_xor(mt, 16));
            mt = fmaxf(mt, __shfl_xor(mt, 32));
            if (!__all(mt - m_ <= 8.0f)) {
                float mnew = fmaxf(m_, mt);
                float alpha = __expf(m_ - mnew);
                float ar[4];
#pragma unroll
                for (int r = 0; r < 4; ++r) ar[r] = __shfl(alpha, 4 * g + r);
#pragma unroll
                for (int dg = 0; dg < 8; ++dg)
#pragma unroll
                    for (int r = 0; r < 4; ++r) acc_o[dg][r] *= ar[r];
                l_ *= alpha;
                m_ = mnew;
            }
            float ps = 0.0f;
#pragma unroll
            for (int n = 0; n < 16; ++n) {
                p[n] = __expf(p[n] - m_);
                ps += p[n];
            }
            ps += __shfl_xor(ps, 16);
            ps += __shfl_xor(ps, 32);
            l_ += ps;

            // ---- PV in two k-halves (Ps reused; same-wave in-order DS) ----
            __builtin_amdgcn_s_setprio(1);
#pragma unroll
            for (int ks = 0; ks < 2; ++ks) {
#pragma unroll
                for (int kh = 0; kh < 2; ++kh) {
                    int kg = 2 * ks + kh;
                    union { __bf16 hv[4]; uint2 u2; } pk;
#pragma unroll
                    for (int r = 0; r < 4; ++r) pk.hv[r] = (__bf16)p[kg * 4 + r];
                    *(uint2*)&Ps[w][l15 * 40 + kh * 16 + g * 4] = pk.u2;
                }
                bf16x8 pf = *(const bf16x8*)&Ps[w][l15 * 40 + g * 8];
#pragma unroll
                for (int dg = 0; dg < 8; ++dg) {
                    int d = dg * 16 + l15;
                    int swz = (ks * 4 + g) ^ ((d >> 3) & 7);
                    bf16x8 vf = *(const bf16x8*)&Vt[d * 64 + swz * 8];
                    acc_o[dg] = __builtin_amdgcn_mfma_f32_16x16x32_bf16(pf, vf, acc_o[dg], 0, 0, 0);
                }
            }
            __builtin_amdgcn_s_setprio(0);

            __syncthreads();          // all waves done reading Vt; drains K DMA + V loads
            if (pref) write_v();      // regs -> Vt for tile kt+1 (loads already landed)
            __syncthreads();          // Vt ready
        }

        // ---- epilogue: O / lsum -> bf16 (global stores only, no LDS) ----
        float lr[4];
#pragma unroll
        for (int r = 0; r < 4; ++r) lr[r] = 1.0f / __shfl(l_, 4 * g + r);
#pragma unroll
        for (int dg = 0; dg < 8; ++dg)
#pragma unroll
            for (int r = 0; r < 4; ++r) {
                int qrow2 = q0 + w * 16 + g * 4 + r;
                om[bbase + (size_t)qrow2 * DD + dg * 16 + l15] =
                    f2bf(acc_o[dg][r] * lr[r]);
            }
    }
}

// ---------------------------------------------------------------------------
extern "C" void kernel_launch(void* const* d_in, const int* in_sizes, int n_in,
                              void* d_out, int out_size, void* d_ws, size_t ws_size,
                              hipStream_t stream) {
    const float* x  = (const float*)d_in[0];
    const float* Wq = (const float*)d_in[1];
    const float* Wk = (const float*)d_in[2];
    const float* Wv = (const float*)d_in[3];
    const float* Wo = (const float*)d_in[4];
    float* out = (float*)d_out;

    char* ws = (char*)d_ws;
    const size_t MD = (size_t)MM * DD;
    const size_t WN = (size_t)DD * DD;
    unsigned short* qb   = (unsigned short*)(ws);            // q,k,v contiguous
    unsigned short* kb   = (unsigned short*)(ws + 2 * MD);
    unsigned short* vb   = (unsigned short*)(ws + 4 * MD);
    unsigned short* ctxb = (unsigned short*)(ws + 6 * MD);
    unsigned short* xb   = (unsigned short*)(ws + 8 * MD);
    unsigned short* wqb  = (unsigned short*)(ws + 10 * MD);  // Wq,Wk,Wv,Wo contiguous
    unsigned short* wob  = (unsigned short*)(ws + 10 * MD + 6 * WN);
    float* cost = (float*)(ws + 10 * MD + 8 * WN);
    float* sint = cost + SS * 64;

    // one fused cast dispatch: x (8192 blocks) + 4 weights (4 x 4096 blocks)
    cast_all<<<8192 + 4 * 4096, 256, 0, stream>>>(x, Wq, Wk, Wv, Wo, xb, wqb);

    rope_table_kernel<<<SS, 64, 0, stream>>>(cost, sint);

    // fused QKV projection: 1536 blocks
    gemm_qkv<<<dim3(48, 32), 256, 0, stream>>>(xb, wqb, qb);

    // RoPE over q and k in one launch (contiguous buffers)
    rope_apply_kernel<<<2 * MM * HH * 16 / 256, 256, 0, stream>>>(qb, cost, sint);

    mfma_attn<<<dim3(16, HH, BB), 256, 0, stream>>>(qb, kb, vb, ctxb);

    gemm_out<<<dim3(16, 32), 256, 0, stream>>>(ctxb, wob, out);
}